// Round 15
// baseline (22525.706 us; speedup 1.0000x reference)
//
#include <hip/hip_runtime.h>
#include <cmath>

constexpr int kB = 32, kS = 32, kE = 512, kH = 8, kV = 10000, kNB = 4;
constexpr int kQ = 3 * kE;  // 1536
constexpr int ROWS = 8;     // rows per tail chunk (A/B vs R12's 4: halves aggregate traffic)
constexpr int TT = 1024;    // tail threads (16 waves)

// ---------------- device scratch ----------------
__device__ float g_w[kB * kS];
__device__ float g_pe[kS * kE];
__device__ float g_Y[kB * kS * kE];
__device__ float g_qkvbuf[kNB][kB * kS * kQ];
__device__ float g_actb[kNB][kB * kS * kE];
__device__ float g_logits[kB * kV];
__device__ float g_U[kNB * kE * kH];
__device__ float g_a0[kNB * kH];
__device__ float g_G[kNB * kH * kE];
__device__ float g_c0[kNB * kE];
__device__ float g_ck[kNB * kE];
__device__ float g_cv[kNB * kE];

// ---------------- setup kernels ----------------
__global__ void onehot_k(float* __restrict__ out) {
    int i = blockIdx.x * 256 + threadIdx.x;
    if (i >= kB * kV) return;
    int b = i / kV, v = i - b * kV;
    out[(size_t)b * kS * kV + v] = (v == 0) ? 1.f : 0.f;
}

__global__ void pe_k(float* __restrict__ pe) {
    int i = blockIdx.x * 256 + threadIdx.x;  // < kS*kE
    int s = i >> 9, e = i & 511;
    int base = e & ~1;
    float div = expf((float)base * (-logf(10000.f) / (float)kE));
    float ang = (float)s * div;
    pe[i] = (e & 1) ? cosf(ang) : sinf(ang);
}

__global__ void compute_w_k(const float* __restrict__ noise, const float* __restrict__ W_in,
                            const float* __restrict__ b_in, float* __restrict__ w) {
    __shared__ float X[kB * kS], T[kB * kS];
    int tid = threadIdx.x;  // 1024
    X[tid] = noise[tid];
    __syncthreads();
    int r = tid >> 5, c = tid & 31;
    float acc = b_in[c];
    for (int k = 0; k < 32; ++k) acc = fmaf(X[r * 32 + k], W_in[k * 32 + c], acc);
    T[tid] = acc;
    __syncthreads();
    acc = b_in[32 + c];
    for (int k = 0; k < 32; ++k) acc = fmaf(T[r * 32 + k], W_in[1024 + k * 32 + c], acc);
    w[tid] = acc;
}

__global__ __launch_bounds__(256) void initY_k(const float* __restrict__ emb,
                                               const float* __restrict__ pe,
                                               float* __restrict__ Y,
                                               const float* __restrict__ Wq0,
                                               const float* __restrict__ bq0,
                                               float* __restrict__ qkv0) {
    __shared__ float ys[kE];
    int b = blockIdx.x, tid = threadIdx.x;
    for (int j = tid; j < kE; j += 256) {
        float v = emb[j] + pe[j];
        Y[(size_t)(b * kS) * kE + j] = v;
        ys[j] = v;
    }
    __syncthreads();
#pragma unroll
    for (int m = 0; m < 6; ++m) {
        int j = tid + 256 * m;
        const float* Wc = Wq0 + (size_t)(j >> 9) * (kE * kE) + (j & 511);
        float acc = bq0[j];
        for (int k = 0; k < kE; ++k) acc = fmaf(ys[k], Wc[(size_t)k * kE], acc);
        qkv0[(size_t)(b * kS) * kQ + j] = acc;
    }
}

// ---- parallel precross (R10-verified) ----
__global__ __launch_bounds__(256) void colsum_k(const float* __restrict__ Wca,
                                                float* __restrict__ ck, float* __restrict__ cv) {
    int n = blockIdx.x, q = blockIdx.y;
    const float* Wk = Wca + (size_t)n * 4 * kE * kE + kE * kE;
    const float* Wv = Wk + kE * kE;
    __shared__ float p1[2][128], p2[2][128];
    int jj = threadIdx.x & 127, half = threadIdx.x >> 7;
    int j = q * 128 + jj;
    float s1 = 0.f, s2 = 0.f;
    for (int e = half * 256; e < half * 256 + 256; ++e) {
        s1 += Wk[(size_t)e * kE + j];
        s2 += Wv[(size_t)e * kE + j];
    }
    p1[half][jj] = s1; p2[half][jj] = s2;
    __syncthreads();
    if (half == 0) {
        ck[n * kE + j] = p1[0][jj] + p1[1][jj];
        cv[n * kE + j] = p2[0][jj] + p2[1][jj];
    }
}

__global__ __launch_bounds__(256) void precross2_k(const float* __restrict__ Wca,
                                                   const float* __restrict__ bca,
                                                   const float* __restrict__ ck,
                                                   const float* __restrict__ cv,
                                                   float* __restrict__ U, float* __restrict__ a0,
                                                   float* __restrict__ G, float* __restrict__ c0) {
    int n = blockIdx.x, s = blockIdx.y;
    const float* Wq = Wca + (size_t)n * 4 * kE * kE;
    const float* Wo = Wq + 3 * kE * kE;
    const float* bq = bca + n * 4 * kE;
    const float* bv = bq + 2 * kE;
    const float* bo = bq + 3 * kE;
    __shared__ float cks[kE], cvs[kE];
    __shared__ float cred[2][128];
    int tid = threadIdx.x;
    for (int p = tid; p < kE; p += 256) { cks[p] = ck[n * kE + p]; cvs[p] = cv[n * kE + p]; }
    __syncthreads();
    for (int p = tid; p < 128 * kH; p += 256) {
        int e = s * 128 + (p >> 3), h = p & 7;
        float acc = 0.f;
        for (int d = 0; d < 64; ++d) acc = fmaf(Wq[(size_t)e * kE + h * 64 + d], cks[h * 64 + d], acc);
        U[n * kE * kH + e * kH + h] = acc;
    }
    for (int p = tid; p < kH * 128; p += 256) {
        int h = p >> 7, j = s * 128 + (p & 127);
        float acc = 0.f;
        for (int d = 0; d < 64; ++d) acc = fmaf(cvs[h * 64 + d], Wo[(size_t)(h * 64 + d) * kE + j], acc);
        G[n * kH * kE + h * kE + j] = acc;
    }
    {
        int jj = tid & 127, half = tid >> 7;
        int j = s * 128 + jj;
        float acc = 0.f;
        for (int e = half * 256; e < half * 256 + 256; ++e) acc = fmaf(bv[e], Wo[(size_t)e * kE + j], acc);
        cred[half][jj] = acc;
        __syncthreads();
        if (half == 0) c0[n * kE + j] = bo[j] + cred[0][jj] + cred[1][jj];
    }
    if (s == 0 && tid < kH) {
        float acc = 0.f;
        for (int d = 0; d < 64; ++d) acc = fmaf(bq[tid * 64 + d], cks[tid * 64 + d], acc);
        a0[n * kH + tid] = acc;
    }
}

// ---------------- 1024-thread (16-wave) helpers ----------------
__device__ __forceinline__ void rowsum8_1024(float v[ROWS], float (*red)[ROWS], float out[ROWS]) {
    int lane = threadIdx.x & 63, w = threadIdx.x >> 6;  // 16 waves
#pragma unroll
    for (int i = 0; i < ROWS; ++i) {
        float s = v[i];
#pragma unroll
        for (int o = 32; o > 0; o >>= 1) s += __shfl_xor(s, o);
        v[i] = s;
    }
    if (lane == 0) {
#pragma unroll
        for (int i = 0; i < ROWS; ++i) red[w][i] = v[i];
    }
    __syncthreads();
#pragma unroll
    for (int i = 0; i < ROWS; ++i) {
        float s = 0.f;
#pragma unroll
        for (int w2 = 0; w2 < 16; ++w2) s += red[w2][i];
        out[i] = s;
    }
    __syncthreads();
}

__device__ __forceinline__ void ln8_1024(float val[ROWS], const float* __restrict__ g,
                                         const float* __restrict__ bb, float (*red)[ROWS], int j,
                                         bool act) {
    float s[ROWS], mean[ROWS], var[ROWS];
#pragma unroll
    for (int i = 0; i < ROWS; ++i) s[i] = act ? val[i] : 0.f;
    rowsum8_1024(s, red, mean);
#pragma unroll
    for (int i = 0; i < ROWS; ++i) {
        mean[i] *= (1.f / (float)kE);
        if (act) val[i] -= mean[i];
        s[i] = act ? val[i] * val[i] : 0.f;
    }
    rowsum8_1024(s, red, var);
#pragma unroll
    for (int i = 0; i < ROWS; ++i) {
        float rstd = rsqrtf(var[i] * (1.f / (float)kE) + 1e-5f);
        if (act) val[i] = g[j] * val[i] * rstd + bb[j];
    }
}

// GEMM phase: 1024 threads = 8 k-groups (kg = tid>>7, 64-k slice) x 128 col-threads
// (jt = tid&127, 4 cols). Same 8x64 k-split, ascending k, same sequential reduce as
// R12 -> bit-identical per-column results (rows are independent accumulators).
__device__ __forceinline__ void gemm_phase4(const float (*in)[kE], const float* __restrict__ W,
                                            float (*out)[kE], int kg, int jt) {
    float acc[ROWS][4];
#pragma unroll
    for (int i = 0; i < ROWS; ++i)
#pragma unroll
        for (int c = 0; c < 4; ++c) acc[i][c] = 0.f;
    const int kbase = kg * 64;
    const int j4 = jt * 4;
#pragma unroll 8
    for (int kk = 0; kk < 64; kk += 4) {
        float4 av[ROWS];
#pragma unroll
        for (int i = 0; i < ROWS; ++i) av[i] = *(const float4*)(&in[i][kbase + kk]);
        const float* Wr = W + (size_t)(kbase + kk) * kE + j4;
        const float4 w0 = *(const float4*)(Wr);
        const float4 w1 = *(const float4*)(Wr + kE);
        const float4 w2 = *(const float4*)(Wr + 2 * kE);
        const float4 w3 = *(const float4*)(Wr + 3 * kE);
#pragma unroll
        for (int i = 0; i < ROWS; ++i) {
            acc[i][0] = fmaf(av[i].x, w0.x, acc[i][0]);
            acc[i][0] = fmaf(av[i].y, w1.x, acc[i][0]);
            acc[i][0] = fmaf(av[i].z, w2.x, acc[i][0]);
            acc[i][0] = fmaf(av[i].w, w3.x, acc[i][0]);
            acc[i][1] = fmaf(av[i].x, w0.y, acc[i][1]);
            acc[i][1] = fmaf(av[i].y, w1.y, acc[i][1]);
            acc[i][1] = fmaf(av[i].z, w2.y, acc[i][1]);
            acc[i][1] = fmaf(av[i].w, w3.y, acc[i][1]);
            acc[i][2] = fmaf(av[i].x, w0.z, acc[i][2]);
            acc[i][2] = fmaf(av[i].y, w1.z, acc[i][2]);
            acc[i][2] = fmaf(av[i].z, w2.z, acc[i][2]);
            acc[i][2] = fmaf(av[i].w, w3.z, acc[i][2]);
            acc[i][3] = fmaf(av[i].x, w0.w, acc[i][3]);
            acc[i][3] = fmaf(av[i].y, w1.w, acc[i][3]);
            acc[i][3] = fmaf(av[i].z, w2.w, acc[i][3]);
            acc[i][3] = fmaf(av[i].w, w3.w, acc[i][3]);
        }
    }
    if (kg == 0) {
#pragma unroll
        for (int i = 0; i < ROWS; ++i)
            *(float4*)(&out[i][j4]) = make_float4(acc[i][0], acc[i][1], acc[i][2], acc[i][3]);
    }
    __syncthreads();
#pragma unroll
    for (int r = 1; r < 8; ++r) {
        if (kg == r) {
#pragma unroll
            for (int i = 0; i < ROWS; ++i) {
                float4 c = *(float4*)(&out[i][j4]);
                c.x += acc[i][0]; c.y += acc[i][1]; c.z += acc[i][2]; c.w += acc[i][3];
                *(float4*)(&out[i][j4]) = c;
            }
        }
        __syncthreads();
    }
}

// ---------------- fused tail: attn+proj+LN+cross+crossLN+FF1+FF2+LN (+QKV next) ----
// grid (kB, nch), 1024 threads (16 waves). ROWS=8.
__global__ __launch_bounds__(1024) void tail8w_k(
    const float* __restrict__ qkv_cur, const float* __restrict__ in_res,
    const float* __restrict__ Wo, const float* __restrict__ bo,
    const float* __restrict__ g0, const float* __restrict__ lb0,
    const float* __restrict__ Um, const float* __restrict__ a0m,
    const float* __restrict__ Gm, const float* __restrict__ c0m,
    const float* __restrict__ g1, const float* __restrict__ lb1,
    const float* __restrict__ W1, const float* __restrict__ fb1,
    const float* __restrict__ W2, const float* __restrict__ fb2,
    const float* __restrict__ g2, const float* __restrict__ lb2,
    const float* __restrict__ wvec, float* __restrict__ act_out,
    const float* __restrict__ Wqn, const float* __restrict__ bqn,
    float* __restrict__ qkv_next, int t, int r0_off) {
    __shared__ float bufA[ROWS][kE];   // 16KB
    __shared__ float bufC[ROWS][kE];   // 16KB
    __shared__ float Us[kE * kH];      // 16KB
    __shared__ float att_s[16][kS];
    __shared__ float alp[ROWS][kH][4];
    __shared__ float om_s[ROWS][kH];
    __shared__ float w_s[kS];
    __shared__ float red[16][ROWS];

    const int b = blockIdx.x;
    const int r0 = r0_off + blockIdx.y * ROWS;
    const int tid = threadIdx.x;
    const int lane = tid & 63, wid = tid >> 6;  // 16 waves
    const int kg = tid >> 7, jt = tid & 127;
    const bool act = (tid < kE);
    int rr[ROWS]; bool valid[ROWS];
#pragma unroll
    for (int i = 0; i < ROWS; ++i) {
        int r = r0 + i;
        valid[i] = (r < t);
        rr[i] = valid[i] ? r : (t - 1);
    }

    // stage Q rows, U, w
    for (int p = tid; p < ROWS * kE; p += TT) {
        int i = p >> 9, d = p & 511;
        bufA[i][d] = qkv_cur[(size_t)(b * kS + rr[i]) * kQ + d];
    }
    for (int p = tid; p < kE * kH; p += TT) Us[p] = Um[p];
    if (tid < t) w_s[tid] = wvec[b * kS + tid];
    __syncthreads();

    // ---- self-attention: wave wid -> row wid&7, heads (wid>>3)*4 .. +3 ----
    {
        const int i = wid & 7;
        const int hb = (wid >> 3) * 4;
#pragma unroll
        for (int hh = 0; hh < 4; ++hh) {
            const int h = hb + hh;
            float sc = -3.0e38f;
            if (lane < t) {
                const float* Kr = qkv_cur + (size_t)(b * kS + lane) * kQ + kE + h * 64;
                float a = 0.f;
#pragma unroll
                for (int d4 = 0; d4 < 16; ++d4) {
                    const float4 kv = *(const float4*)(Kr + d4 * 4);
                    const float4 qv = *(const float4*)(&bufA[i][h * 64 + d4 * 4]);
                    a = fmaf(qv.x, kv.x, a); a = fmaf(qv.y, kv.y, a);
                    a = fmaf(qv.z, kv.z, a); a = fmaf(qv.w, kv.w, a);
                }
                sc = a * 0.125f;
            }
            float m = sc;
#pragma unroll
            for (int o = 32; o > 0; o >>= 1) m = fmaxf(m, __shfl_xor(m, o));
            float e = (lane < t) ? expf(sc - m) : 0.f;
            float ss = e;
#pragma unroll
            for (int o = 32; o > 0; o >>= 1) ss += __shfl_xor(ss, o);
            if (lane < t) att_s[wid][lane] = e / ss;
            float acc = 0.f;
            const float* Vb = qkv_cur + (size_t)(b * kS) * kQ + 2 * kE + h * 64 + lane;
            for (int k = 0; k < t; ++k) acc = fmaf(att_s[wid][k], Vb[(size_t)k * kQ], acc);
            bufA[i][h * 64 + lane] = acc;  // own (row, head-slice); disjoint across waves
        }
    }
    __syncthreads();

    float val[ROWS], hreg[ROWS], h2reg[ROWS];

    // ---- proj + residual + LN -> h ----
    float resv[ROWS];
#pragma unroll
    for (int i = 0; i < ROWS; ++i)
        resv[i] = act ? in_res[(size_t)(b * kS + rr[i]) * kE + tid] : 0.f;
    gemm_phase4(bufA, Wo, bufC, kg, jt);
    {
        float btid = act ? bo[tid] : 0.f;
#pragma unroll
        for (int i = 0; i < ROWS; ++i) val[i] = act ? (bufC[i][tid] + btid + resv[i]) : 0.f;
        ln8_1024(val, g0, lb0, red, act ? tid : 0, act);
#pragma unroll
        for (int i = 0; i < ROWS; ++i) {
            hreg[i] = val[i];
            if (act) bufA[i][tid] = val[i];
        }
    }
    __syncthreads();

    // ---- reduced cross-attn ----
    if (tid < ROWS * kH * 4) {  // 256 threads
        int i = tid >> 5, h = (tid >> 2) & 7, cs = tid & 3;
        float a = 0.f;
        for (int e = cs * 128; e < cs * 128 + 128; ++e) a = fmaf(bufA[i][e], Us[e * kH + h], a);
        alp[i][h][cs] = a;
    }
    __syncthreads();
    if (tid < ROWS * kH) {  // 64 threads
        int i = tid >> 3, h = tid & 7;
        float a = a0m[h] + alp[i][h][0] + alp[i][h][1] + alp[i][h][2] + alp[i][h][3];
        a *= 0.125f;
        float mm = -3.0e38f;
        for (int s = 0; s < t; ++s) mm = fmaxf(mm, a * w_s[s]);
        float se = 0.f, sw = 0.f;
        for (int s = 0; s < t; ++s) {
            float ex = expf(a * w_s[s] - mm);
            se += ex;
            sw = fmaf(ex, w_s[s], sw);
        }
        om_s[i][h] = sw / se;
    }
    __syncthreads();

    // ---- crossout + residual(h) + LN -> h2 ----
    {
        float ctid = act ? c0m[tid] : 0.f;
#pragma unroll
        for (int i = 0; i < ROWS; ++i) {
            float v = ctid + hreg[i];
            if (act) {
#pragma unroll
                for (int h = 0; h < kH; ++h) v = fmaf(om_s[i][h], Gm[h * kE + tid], v);
            }
            val[i] = act ? v : 0.f;
        }
        ln8_1024(val, g1, lb1, red, act ? tid : 0, act);
#pragma unroll
        for (int i = 0; i < ROWS; ++i) {
            h2reg[i] = val[i];
            if (act) bufA[i][tid] = val[i];
        }
    }
    __syncthreads();

    // ---- FF1 + relu ----
    gemm_phase4(bufA, W1, bufC, kg, jt);
    {
        float btid = act ? fb1[tid] : 0.f;
#pragma unroll
        for (int i = 0; i < ROWS; ++i) val[i] = act ? fmaxf(bufC[i][tid] + btid, 0.f) : 0.f;
    }
    __syncthreads();  // all FF1 reads of bufA done
    {
#pragma unroll
        for (int i = 0; i < ROWS; ++i)
            if (act) bufA[i][tid] = val[i];
    }
    __syncthreads();

    // ---- FF2 + residual(h2) + LN -> act_out (+ stage act for fused QKV) ----
    gemm_phase4(bufA, W2, bufC, kg, jt);
    {
        float btid = act ? fb2[tid] : 0.f;
#pragma unroll
        for (int i = 0; i < ROWS; ++i) val[i] = act ? (bufC[i][tid] + btid + h2reg[i]) : 0.f;
        ln8_1024(val, g2, lb2, red, act ? tid : 0, act);
    }
    __syncthreads();  // all FF2 reads of bufA done
    {
#pragma unroll
        for (int i = 0; i < ROWS; ++i) {
            if (act) {
                if (valid[i]) act_out[(size_t)(b * kS + r0 + i) * kE + tid] = val[i];
                bufA[i][tid] = val[i];
            }
        }
    }
    __syncthreads();

    // ---- fused QKV projection for next decoder block (row-local) ----
    if (Wqn != nullptr) {
#pragma unroll
        for (int slab = 0; slab < 3; ++slab) {
            gemm_phase4(bufA, Wqn + (size_t)slab * kE * kE, bufC, kg, jt);
            if (act) {
                float bj = bqn[slab * kE + tid];
#pragma unroll
                for (int i = 0; i < ROWS; ++i)
                    if (valid[i])
                        qkv_next[(size_t)(b * kS + r0 + i) * kQ + slab * kE + tid] =
                            bufC[i][tid] + bj;
            }
            __syncthreads();
        }
    }
}

// ---------------- logits: grid (157), 64 cols/block, all 32 batch rows in LDS ----------------
__global__ __launch_bounds__(256) void logits_k(const float* __restrict__ act3,
                                                const float* __restrict__ softW,
                                                const float* __restrict__ softb,
                                                float* __restrict__ logits, int tokm1) {
    __shared__ float xs[kB][kE];  // 64KB
    int tid = threadIdx.x;
    for (int p = tid; p < kB * kE; p += 256) {
        int bb = p >> 9, k = p & 511;
        xs[bb][k] = act3[(size_t)(bb * kS + tokm1) * kE + k];
    }
    __syncthreads();
    const int tx = tid & 31, ty = tid >> 5;
    int j0 = blockIdx.x * 64 + 2 * tx;
    int j0c = (j0 + 1 < kV) ? j0 : (kV - 2);
    float acc[4][2];
#pragma unroll
    for (int r = 0; r < 4; ++r) { acc[r][0] = softb[j0c]; acc[r][1] = softb[j0c + 1]; }
#pragma unroll 8
    for (int k = 0; k < kE; ++k) {
        const float2 wv = *(const float2*)(softW + (size_t)k * kV + j0c);
#pragma unroll
        for (int r = 0; r < 4; ++r) {
            float xv = xs[4 * ty + r][k];
            acc[r][0] = fmaf(xv, wv.x, acc[r][0]);
            acc[r][1] = fmaf(xv, wv.y, acc[r][1]);
        }
    }
    if (j0 + 1 < kV) {
#pragma unroll
        for (int r = 0; r < 4; ++r) {
            logits[(size_t)(4 * ty + r) * kV + j0] = acc[r][0];
            logits[(size_t)(4 * ty + r) * kV + j0 + 1] = acc[r][1];
        }
    } else if (j0 < kV) {
#pragma unroll
        for (int r = 0; r < 4; ++r) logits[(size_t)(4 * ty + r) * kV + j0] = acc[r][0];
    }
}

// ---------------- softmax + argmax + probs + Y row ----------------
__global__ __launch_bounds__(256) void softargmax_k(const float* __restrict__ logits,
                                                    float* __restrict__ outp,
                                                    const float* __restrict__ emb,
                                                    const float* __restrict__ pe_t,
                                                    float* __restrict__ Y, int tok) {
    __shared__ float redf[4];
    __shared__ int redi[4];
    int b = blockIdx.x, tid = threadIdx.x;
    const float* lg = logits + (size_t)b * kV;
    float m = -3.4e38f;
    int mi = 0;
    for (int j = tid; j < kV; j += 256) {
        float v = lg[j];
        if (v > m) { m = v; mi = j; }
    }
#pragma unroll
    for (int o = 32; o > 0; o >>= 1) {
        float m2 = __shfl_xor(m, o);
        int i2 = __shfl_xor(mi, o);
        if (m2 > m || (m2 == m && i2 < mi)) { m = m2; mi = i2; }
    }
    int wid = tid >> 6;
    if ((tid & 63) == 0) { redf[wid] = m; redi[wid] = mi; }
    __syncthreads();
    m = redf[0]; mi = redi[0];
#pragma unroll
    for (int wv = 1; wv < 4; ++wv) {
        if (redf[wv] > m || (redf[wv] == m && redi[wv] < mi)) { m = redf[wv]; mi = redi[wv]; }
    }
    __syncthreads();
    float ssum = 0.f;
    for (int j = tid; j < kV; j += 256) ssum += expf(lg[j] - m);
    {
#pragma unroll
        for (int o = 32; o > 0; o >>= 1) ssum += __shfl_xor(ssum, o);
        if ((tid & 63) == 0) redf[wid] = ssum;
        __syncthreads();
        ssum = redf[0] + redf[1] + redf[2] + redf[3];
    }
    float inv = 1.f / ssum;
    float* orow = outp + (size_t)b * ((size_t)kS * kV);
    for (int j = tid; j < kV; j += 256) orow[j] = expf(lg[j] - m) * inv;
    const float* erow = emb + (size_t)mi * kE;
    float* yrow = Y + (size_t)(b * kS + tok) * kE;
    for (int j = tid; j < kE; j += 256) yrow[j] = erow[j] + pe_t[j];
}

// ---------------- qkv0 row for new token, batch-shared: grid (24) (R5-verified) ----------------
__global__ __launch_bounds__(256) void qkvrow_k(const float* __restrict__ Y,
                                                const float* __restrict__ Wq0,
                                                const float* __restrict__ bq0,
                                                float* __restrict__ qkv0, int tok) {
    __shared__ float ys[kB][kE];  // 64KB
    int tid = threadIdx.x;
    for (int p = tid; p < kB * kE; p += 256) {
        int bb = p >> 9, k = p & 511;
        ys[bb][k] = Y[(size_t)(bb * kS + tok) * kE + k];
    }
    __syncthreads();
    const int tx = tid & 63, ty = tid >> 6;
    const int j = blockIdx.x * 64 + tx;
    const float* Wc = Wq0 + (size_t)(j >> 9) * (kE * kE) + (j & 511);
    float acc[8];
    float bj = bq0[j];
#pragma unroll
    for (int i = 0; i < 8; ++i) acc[i] = bj;
#pragma unroll 4
    for (int k = 0; k < kE; k += 4) {
        float w0 = Wc[(size_t)(k + 0) * kE];
        float w1 = Wc[(size_t)(k + 1) * kE];
        float w2 = Wc[(size_t)(k + 2) * kE];
        float w3 = Wc[(size_t)(k + 3) * kE];
#pragma unroll
        for (int i = 0; i < 8; ++i) {
            const float4 yv = *(const float4*)(&ys[ty * 8 + i][k]);
            float a = acc[i];
            a = fmaf(yv.x, w0, a);
            a = fmaf(yv.y, w1, a);
            a = fmaf(yv.z, w2, a);
            a = fmaf(yv.w, w3, a);
            acc[i] = a;
        }
    }
#pragma unroll
    for (int i = 0; i < 8; ++i)
        qkv0[(size_t)((ty * 8 + i) * kS + tok) * kQ + j] = acc[i];
}

// ---------------- host ----------------
extern "C" void kernel_launch(void* const* d_in, const int* in_sizes, int n_in, void* d_out,
                              int out_size, void* d_ws, size_t ws_size, hipStream_t stream) {
    const float* noise = (const float*)d_in[0];
    const float* W_in = (const float*)d_in[1];
    const float* b_in = (const float*)d_in[2];
    const float* emb = (const float*)d_in[3];
    const float* Wsa = (const float*)d_in[4];
    const float* bsa = (const float*)d_in[5];
    const float* Wca = (const float*)d_in[6];
    const float* bca = (const float*)d_in[7];
    const float* Wff = (const float*)d_in[8];
    const float* bff = (const float*)d_in[9];
    const float* ln_g = (const float*)d_in[10];
    const float* ln_b = (const float*)d_in[11];
    const float* softW = (const float*)d_in[12];
    const float* softb = (const float*)d_in[13];
    float* out = (float*)d_out;
    (void)d_ws; (void)ws_size; (void)in_sizes; (void)n_in; (void)out_size;

    float *w_, *pe_, *Y_, *qkvb_, *actb_, *lg_, *U_, *a0_, *G_, *c0_, *ck_, *cv_;
    hipGetSymbolAddress((void**)&w_, HIP_SYMBOL(g_w));
    hipGetSymbolAddress((void**)&pe_, HIP_SYMBOL(g_pe));
    hipGetSymbolAddress((void**)&Y_, HIP_SYMBOL(g_Y));
    hipGetSymbolAddress((void**)&qkvb_, HIP_SYMBOL(g_qkvbuf));
    hipGetSymbolAddress((void**)&actb_, HIP_SYMBOL(g_actb));
    hipGetSymbolAddress((void**)&lg_, HIP_SYMBOL(g_logits));
    hipGetSymbolAddress((void**)&U_, HIP_SYMBOL(g_U));
    hipGetSymbolAddress((void**)&a0_, HIP_SYMBOL(g_a0));
    hipGetSymbolAddress((void**)&G_, HIP_SYMBOL(g_G));
    hipGetSymbolAddress((void**)&c0_, HIP_SYMBOL(g_c0));
    hipGetSymbolAddress((void**)&ck_, HIP_SYMBOL(g_ck));
    hipGetSymbolAddress((void**)&cv_, HIP_SYMBOL(g_cv));

    float* qb[kNB];
    float* ab[kNB];
    for (int n = 0; n < kNB; ++n) {
        qb[n] = qkvb_ + (size_t)n * (kB * kS * kQ);
        ab[n] = actb_ + (size_t)n * (kB * kS * kE);
    }

    dim3 blk(256);
    hipLaunchKernelGGL(onehot_k, dim3((kB * kV + 255) / 256), blk, 0, stream, out);
    hipLaunchKernelGGL(pe_k, dim3(kS * kE / 256), blk, 0, stream, pe_);
    hipLaunchKernelGGL(compute_w_k, dim3(1), dim3(1024), 0, stream, noise, W_in, b_in, w_);
    hipLaunchKernelGGL(initY_k, dim3(kB), blk, 0, stream, emb, pe_, Y_, Wsa, bsa, qb[0]);
    hipLaunchKernelGGL(colsum_k, dim3(kNB, 4), blk, 0, stream, Wca, ck_, cv_);
    hipLaunchKernelGGL(precross2_k, dim3(kNB, 4), blk, 0, stream, Wca, bca, ck_, cv_, U_, a0_,
                       G_, c0_);

    for (int tok = 1; tok < kS; ++tok) {
        const int t = tok;
        const int nch = (t + ROWS - 1) / ROWS;
        for (int n = 0; n < kNB; ++n) {
            const float* in_res = (n == 0) ? Y_ : ab[n - 1];
            const float* Wn = Wsa + (size_t)n * 4 * kE * kE;
            const float* bn = bsa + (size_t)n * 4 * kE;
            const float* Wf = Wff + (size_t)n * 2 * kE * kE;
            const float* bf = bff + (size_t)n * 2 * kE;
            const float* Wqn = (n < 3) ? (Wsa + (size_t)(n + 1) * 4 * kE * kE) : nullptr;
            const float* bqn = (n < 3) ? (bsa + (size_t)(n + 1) * 4 * kE) : bsa;
            float* qnext = (n < 3) ? qb[n + 1] : nullptr;
            // block 3's output is only consumed at row t-1 -> single chunk covering it
            const int grid_y = (n == 3) ? 1 : nch;
            const int r0_off = (n == 3) ? ((t > ROWS) ? (t - ROWS) : 0) : 0;
            hipLaunchKernelGGL(tail8w_k, dim3(kB, grid_y), dim3(TT), 0, stream,
                               qb[n], in_res,
                               Wn + 3 * kE * kE, bn + 3 * kE,
                               ln_g + (size_t)(n * 3 + 0) * kE, ln_b + (size_t)(n * 3 + 0) * kE,
                               U_ + n * kE * kH, a0_ + n * kH, G_ + n * kH * kE, c0_ + n * kE,
                               ln_g + (size_t)(n * 3 + 1) * kE, ln_b + (size_t)(n * 3 + 1) * kE,
                               Wf, bf, Wf + kE * kE, bf + kE,
                               ln_g + (size_t)(n * 3 + 2) * kE, ln_b + (size_t)(n * 3 + 2) * kE,
                               w_, ab[n], Wqn, bqn, qnext, t, r0_off);
        }
        hipLaunchKernelGGL(logits_k, dim3(157), blk, 0, stream, ab[3], softW, softb, lg_,
                           tok - 1);
        hipLaunchKernelGGL(softargmax_k, dim3(kB), blk, 0, stream, lg_,
                           out + (size_t)tok * kV, emb, pe_ + (size_t)tok * kE, Y_, tok);
        hipLaunchKernelGGL(qkvrow_k, dim3(24), blk, 0, stream, Y_, Wsa, bsa, qb[0], tok);
    }
}

// Round 16
// 12997.803 us; speedup vs baseline: 1.7330x; 1.7330x over previous
//
#include <hip/hip_runtime.h>
#include <cmath>

constexpr int kB = 32, kS = 32, kE = 512, kH = 8, kV = 10000, kNB = 4;
constexpr int kQ = 3 * kE;  // 1536
constexpr int ROWS = 4;     // rows per tail chunk (R12-verified optimum)
constexpr int TT = 1024;    // tail threads (16 waves)

// ---------------- device scratch ----------------
__device__ float g_w[kB * kS];
__device__ float g_pe[kS * kE];
__device__ float g_Y[kB * kS * kE];
__device__ float g_qkvbuf[kNB][kB * kS * kQ];
__device__ float g_actb[kNB][kB * kS * kE];
__device__ float g_logits[kB * kV];
__device__ float g_U[kNB * kE * kH];
__device__ float g_a0[kNB * kH];
__device__ float g_G[kNB * kH * kE];
__device__ float g_c0[kNB * kE];
__device__ float g_ck[kNB * kE];
__device__ float g_cv[kNB * kE];

// ---------------- setup kernels ----------------
__global__ void onehot_k(float* __restrict__ out) {
    int i = blockIdx.x * 256 + threadIdx.x;
    if (i >= kB * kV) return;
    int b = i / kV, v = i - b * kV;
    out[(size_t)b * kS * kV + v] = (v == 0) ? 1.f : 0.f;
}

__global__ void pe_k(float* __restrict__ pe) {
    int i = blockIdx.x * 256 + threadIdx.x;  // < kS*kE
    int s = i >> 9, e = i & 511;
    int base = e & ~1;
    float div = expf((float)base * (-logf(10000.f) / (float)kE));
    float ang = (float)s * div;
    pe[i] = (e & 1) ? cosf(ang) : sinf(ang);
}

__global__ void compute_w_k(const float* __restrict__ noise, const float* __restrict__ W_in,
                            const float* __restrict__ b_in, float* __restrict__ w) {
    __shared__ float X[kB * kS], T[kB * kS];
    int tid = threadIdx.x;  // 1024
    X[tid] = noise[tid];
    __syncthreads();
    int r = tid >> 5, c = tid & 31;
    float acc = b_in[c];
    for (int k = 0; k < 32; ++k) acc = fmaf(X[r * 32 + k], W_in[k * 32 + c], acc);
    T[tid] = acc;
    __syncthreads();
    acc = b_in[32 + c];
    for (int k = 0; k < 32; ++k) acc = fmaf(T[r * 32 + k], W_in[1024 + k * 32 + c], acc);
    w[tid] = acc;
}

__global__ __launch_bounds__(256) void initY_k(const float* __restrict__ emb,
                                               const float* __restrict__ pe,
                                               float* __restrict__ Y,
                                               const float* __restrict__ Wq0,
                                               const float* __restrict__ bq0,
                                               float* __restrict__ qkv0) {
    __shared__ float ys[kE];
    int b = blockIdx.x, tid = threadIdx.x;
    for (int j = tid; j < kE; j += 256) {
        float v = emb[j] + pe[j];
        Y[(size_t)(b * kS) * kE + j] = v;
        ys[j] = v;
    }
    __syncthreads();
#pragma unroll
    for (int m = 0; m < 6; ++m) {
        int j = tid + 256 * m;
        const float* Wc = Wq0 + (size_t)(j >> 9) * (kE * kE) + (j & 511);
        float acc = bq0[j];
        for (int k = 0; k < kE; ++k) acc = fmaf(ys[k], Wc[(size_t)k * kE], acc);
        qkv0[(size_t)(b * kS) * kQ + j] = acc;
    }
}

// ---- parallel precross (R10-verified) ----
__global__ __launch_bounds__(256) void colsum_k(const float* __restrict__ Wca,
                                                float* __restrict__ ck, float* __restrict__ cv) {
    int n = blockIdx.x, q = blockIdx.y;
    const float* Wk = Wca + (size_t)n * 4 * kE * kE + kE * kE;
    const float* Wv = Wk + kE * kE;
    __shared__ float p1[2][128], p2[2][128];
    int jj = threadIdx.x & 127, half = threadIdx.x >> 7;
    int j = q * 128 + jj;
    float s1 = 0.f, s2 = 0.f;
    for (int e = half * 256; e < half * 256 + 256; ++e) {
        s1 += Wk[(size_t)e * kE + j];
        s2 += Wv[(size_t)e * kE + j];
    }
    p1[half][jj] = s1; p2[half][jj] = s2;
    __syncthreads();
    if (half == 0) {
        ck[n * kE + j] = p1[0][jj] + p1[1][jj];
        cv[n * kE + j] = p2[0][jj] + p2[1][jj];
    }
}

__global__ __launch_bounds__(256) void precross2_k(const float* __restrict__ Wca,
                                                   const float* __restrict__ bca,
                                                   const float* __restrict__ ck,
                                                   const float* __restrict__ cv,
                                                   float* __restrict__ U, float* __restrict__ a0,
                                                   float* __restrict__ G, float* __restrict__ c0) {
    int n = blockIdx.x, s = blockIdx.y;
    const float* Wq = Wca + (size_t)n * 4 * kE * kE;
    const float* Wo = Wq + 3 * kE * kE;
    const float* bq = bca + n * 4 * kE;
    const float* bv = bq + 2 * kE;
    const float* bo = bq + 3 * kE;
    __shared__ float cks[kE], cvs[kE];
    __shared__ float cred[2][128];
    int tid = threadIdx.x;
    for (int p = tid; p < kE; p += 256) { cks[p] = ck[n * kE + p]; cvs[p] = cv[n * kE + p]; }
    __syncthreads();
    for (int p = tid; p < 128 * kH; p += 256) {
        int e = s * 128 + (p >> 3), h = p & 7;
        float acc = 0.f;
        for (int d = 0; d < 64; ++d) acc = fmaf(Wq[(size_t)e * kE + h * 64 + d], cks[h * 64 + d], acc);
        U[n * kE * kH + e * kH + h] = acc;
    }
    for (int p = tid; p < kH * 128; p += 256) {
        int h = p >> 7, j = s * 128 + (p & 127);
        float acc = 0.f;
        for (int d = 0; d < 64; ++d) acc = fmaf(cvs[h * 64 + d], Wo[(size_t)(h * 64 + d) * kE + j], acc);
        G[n * kH * kE + h * kE + j] = acc;
    }
    {
        int jj = tid & 127, half = tid >> 7;
        int j = s * 128 + jj;
        float acc = 0.f;
        for (int e = half * 256; e < half * 256 + 256; ++e) acc = fmaf(bv[e], Wo[(size_t)e * kE + j], acc);
        cred[half][jj] = acc;
        __syncthreads();
        if (half == 0) c0[n * kE + j] = bo[j] + cred[0][jj] + cred[1][jj];
    }
    if (s == 0 && tid < kH) {
        float acc = 0.f;
        for (int d = 0; d < 64; ++d) acc = fmaf(bq[tid * 64 + d], cks[tid * 64 + d], acc);
        a0[n * kH + tid] = acc;
    }
}

// ---------------- 1024-thread (16-wave) helpers (R12-verified) ----------------
__device__ __forceinline__ void rowsum4_1024(float v[ROWS], float (*red)[ROWS], float out[ROWS]) {
    int lane = threadIdx.x & 63, w = threadIdx.x >> 6;  // 16 waves
#pragma unroll
    for (int i = 0; i < ROWS; ++i) {
        float s = v[i];
#pragma unroll
        for (int o = 32; o > 0; o >>= 1) s += __shfl_xor(s, o);
        v[i] = s;
    }
    if (lane == 0) {
#pragma unroll
        for (int i = 0; i < ROWS; ++i) red[w][i] = v[i];
    }
    __syncthreads();
#pragma unroll
    for (int i = 0; i < ROWS; ++i) {
        float s = 0.f;
#pragma unroll
        for (int w2 = 0; w2 < 16; ++w2) s += red[w2][i];
        out[i] = s;
    }
    __syncthreads();
}

__device__ __forceinline__ void ln4_1024(float val[ROWS], const float* __restrict__ g,
                                         const float* __restrict__ bb, float (*red)[ROWS], int j,
                                         bool act) {
    float s[ROWS], mean[ROWS], var[ROWS];
#pragma unroll
    for (int i = 0; i < ROWS; ++i) s[i] = act ? val[i] : 0.f;
    rowsum4_1024(s, red, mean);
#pragma unroll
    for (int i = 0; i < ROWS; ++i) {
        mean[i] *= (1.f / (float)kE);
        if (act) val[i] -= mean[i];
        s[i] = act ? val[i] * val[i] : 0.f;
    }
    rowsum4_1024(s, red, var);
#pragma unroll
    for (int i = 0; i < ROWS; ++i) {
        float rstd = rsqrtf(var[i] * (1.f / (float)kE) + 1e-5f);
        if (act) val[i] = g[j] * val[i] * rstd + bb[j];
    }
}

// GEMM phase (R12-verified): 1024 threads = 8 k-groups (kg = tid>>7, 64-k slice) x 128
// col-threads (jt = tid&127, 4 cols). Ascending k, sequential k-group reduce.
__device__ __forceinline__ void gemm_phase4(const float (*in)[kE], const float* __restrict__ W,
                                            float (*out)[kE], int kg, int jt) {
    float acc[ROWS][4];
#pragma unroll
    for (int i = 0; i < ROWS; ++i)
#pragma unroll
        for (int c = 0; c < 4; ++c) acc[i][c] = 0.f;
    const int kbase = kg * 64;
    const int j4 = jt * 4;
#pragma unroll 8
    for (int kk = 0; kk < 64; kk += 4) {
        float4 av[ROWS];
#pragma unroll
        for (int i = 0; i < ROWS; ++i) av[i] = *(const float4*)(&in[i][kbase + kk]);
        const float* Wr = W + (size_t)(kbase + kk) * kE + j4;
        const float4 w0 = *(const float4*)(Wr);
        const float4 w1 = *(const float4*)(Wr + kE);
        const float4 w2 = *(const float4*)(Wr + 2 * kE);
        const float4 w3 = *(const float4*)(Wr + 3 * kE);
#pragma unroll
        for (int i = 0; i < ROWS; ++i) {
            acc[i][0] = fmaf(av[i].x, w0.x, acc[i][0]);
            acc[i][0] = fmaf(av[i].y, w1.x, acc[i][0]);
            acc[i][0] = fmaf(av[i].z, w2.x, acc[i][0]);
            acc[i][0] = fmaf(av[i].w, w3.x, acc[i][0]);
            acc[i][1] = fmaf(av[i].x, w0.y, acc[i][1]);
            acc[i][1] = fmaf(av[i].y, w1.y, acc[i][1]);
            acc[i][1] = fmaf(av[i].z, w2.y, acc[i][1]);
            acc[i][1] = fmaf(av[i].w, w3.y, acc[i][1]);
            acc[i][2] = fmaf(av[i].x, w0.z, acc[i][2]);
            acc[i][2] = fmaf(av[i].y, w1.z, acc[i][2]);
            acc[i][2] = fmaf(av[i].z, w2.z, acc[i][2]);
            acc[i][2] = fmaf(av[i].w, w3.z, acc[i][2]);
            acc[i][3] = fmaf(av[i].x, w0.w, acc[i][3]);
            acc[i][3] = fmaf(av[i].y, w1.w, acc[i][3]);
            acc[i][3] = fmaf(av[i].z, w2.w, acc[i][3]);
            acc[i][3] = fmaf(av[i].w, w3.w, acc[i][3]);
        }
    }
    if (kg == 0) {
#pragma unroll
        for (int i = 0; i < ROWS; ++i)
            *(float4*)(&out[i][j4]) = make_float4(acc[i][0], acc[i][1], acc[i][2], acc[i][3]);
    }
    __syncthreads();
#pragma unroll
    for (int r = 1; r < 8; ++r) {
        if (kg == r) {
#pragma unroll
            for (int i = 0; i < ROWS; ++i) {
                float4 c = *(float4*)(&out[i][j4]);
                c.x += acc[i][0]; c.y += acc[i][1]; c.z += acc[i][2]; c.w += acc[i][3];
                *(float4*)(&out[i][j4]) = c;
            }
        }
        __syncthreads();
    }
}

// ---------------- fused tail (R12-verified): attn+proj+LN+cross+crossLN+FF1+FF2+LN+QKV ----
__global__ __launch_bounds__(1024) void tail4w_k(
    const float* __restrict__ qkv_cur, const float* __restrict__ in_res,
    const float* __restrict__ Wo, const float* __restrict__ bo,
    const float* __restrict__ g0, const float* __restrict__ lb0,
    const float* __restrict__ Um, const float* __restrict__ a0m,
    const float* __restrict__ Gm, const float* __restrict__ c0m,
    const float* __restrict__ g1, const float* __restrict__ lb1,
    const float* __restrict__ W1, const float* __restrict__ fb1,
    const float* __restrict__ W2, const float* __restrict__ fb2,
    const float* __restrict__ g2, const float* __restrict__ lb2,
    const float* __restrict__ wvec, float* __restrict__ act_out,
    const float* __restrict__ Wqn, const float* __restrict__ bqn,
    float* __restrict__ qkv_next, int t, int r0_off) {
    __shared__ float bufA[ROWS][kE];   // 8KB
    __shared__ float bufC[ROWS][kE];   // 8KB
    __shared__ float Us[kE * kH];      // 16KB
    __shared__ float att_s[16][kS];
    __shared__ float alp[ROWS][kH][4];
    __shared__ float om_s[ROWS][kH];
    __shared__ float w_s[kS];
    __shared__ float red[16][ROWS];

    const int b = blockIdx.x;
    const int r0 = r0_off + blockIdx.y * ROWS;
    const int tid = threadIdx.x;
    const int lane = tid & 63, wid = tid >> 6;  // 16 waves
    const int kg = tid >> 7, jt = tid & 127;
    const bool act = (tid < kE);
    int rr[ROWS]; bool valid[ROWS];
#pragma unroll
    for (int i = 0; i < ROWS; ++i) {
        int r = r0 + i;
        valid[i] = (r < t);
        rr[i] = valid[i] ? r : (t - 1);
    }

    // stage Q rows, U, w
    for (int p = tid; p < ROWS * kE; p += TT) {
        int i = p >> 9, d = p & 511;
        bufA[i][d] = qkv_cur[(size_t)(b * kS + rr[i]) * kQ + d];
    }
    for (int p = tid; p < kE * kH; p += TT) Us[p] = Um[p];
    if (tid < t) w_s[tid] = wvec[b * kS + tid];
    __syncthreads();

    // ---- self-attention: wave wid -> row wid&3, heads (wid>>2)*2 .. +1 ----
    {
        const int i = wid & 3;
        const int hb = (wid >> 2) * 2;
#pragma unroll
        for (int hh = 0; hh < 2; ++hh) {
            const int h = hb + hh;
            float sc = -3.0e38f;
            if (lane < t) {
                const float* Kr = qkv_cur + (size_t)(b * kS + lane) * kQ + kE + h * 64;
                float a = 0.f;
#pragma unroll
                for (int d4 = 0; d4 < 16; ++d4) {
                    const float4 kv = *(const float4*)(Kr + d4 * 4);
                    const float4 qv = *(const float4*)(&bufA[i][h * 64 + d4 * 4]);
                    a = fmaf(qv.x, kv.x, a); a = fmaf(qv.y, kv.y, a);
                    a = fmaf(qv.z, kv.z, a); a = fmaf(qv.w, kv.w, a);
                }
                sc = a * 0.125f;
            }
            float m = sc;
#pragma unroll
            for (int o = 32; o > 0; o >>= 1) m = fmaxf(m, __shfl_xor(m, o));
            float e = (lane < t) ? expf(sc - m) : 0.f;
            float ss = e;
#pragma unroll
            for (int o = 32; o > 0; o >>= 1) ss += __shfl_xor(ss, o);
            if (lane < t) att_s[wid][lane] = e / ss;
            float acc = 0.f;
            const float* Vb = qkv_cur + (size_t)(b * kS) * kQ + 2 * kE + h * 64 + lane;
            for (int k = 0; k < t; ++k) acc = fmaf(att_s[wid][k], Vb[(size_t)k * kQ], acc);
            bufA[i][h * 64 + lane] = acc;  // own (row, head-slice); disjoint across waves
        }
    }
    __syncthreads();

    float val[ROWS], hreg[ROWS], h2reg[ROWS];

    // ---- proj + residual + LN -> h ----
    float resv[ROWS];
#pragma unroll
    for (int i = 0; i < ROWS; ++i)
        resv[i] = act ? in_res[(size_t)(b * kS + rr[i]) * kE + tid] : 0.f;
    gemm_phase4(bufA, Wo, bufC, kg, jt);
    {
        float btid = act ? bo[tid] : 0.f;
#pragma unroll
        for (int i = 0; i < ROWS; ++i) val[i] = act ? (bufC[i][tid] + btid + resv[i]) : 0.f;
        ln4_1024(val, g0, lb0, red, act ? tid : 0, act);
#pragma unroll
        for (int i = 0; i < ROWS; ++i) {
            hreg[i] = val[i];
            if (act) bufA[i][tid] = val[i];
        }
    }
    __syncthreads();

    // ---- reduced cross-attn ----
    if (tid < ROWS * kH * 4) {  // 128 threads
        int i = tid >> 5, h = (tid >> 2) & 7, cs = tid & 3;
        float a = 0.f;
        for (int e = cs * 128; e < cs * 128 + 128; ++e) a = fmaf(bufA[i][e], Us[e * kH + h], a);
        alp[i][h][cs] = a;
    }
    __syncthreads();
    if (tid < ROWS * kH) {  // 32 threads
        int i = tid >> 3, h = tid & 7;
        float a = a0m[h] + alp[i][h][0] + alp[i][h][1] + alp[i][h][2] + alp[i][h][3];
        a *= 0.125f;
        float mm = -3.0e38f;
        for (int s = 0; s < t; ++s) mm = fmaxf(mm, a * w_s[s]);
        float se = 0.f, sw = 0.f;
        for (int s = 0; s < t; ++s) {
            float ex = expf(a * w_s[s] - mm);
            se += ex;
            sw = fmaf(ex, w_s[s], sw);
        }
        om_s[i][h] = sw / se;
    }
    __syncthreads();

    // ---- crossout + residual(h) + LN -> h2 ----
    {
        float ctid = act ? c0m[tid] : 0.f;
#pragma unroll
        for (int i = 0; i < ROWS; ++i) {
            float v = ctid + hreg[i];
            if (act) {
#pragma unroll
                for (int h = 0; h < kH; ++h) v = fmaf(om_s[i][h], Gm[h * kE + tid], v);
            }
            val[i] = act ? v : 0.f;
        }
        ln4_1024(val, g1, lb1, red, act ? tid : 0, act);
#pragma unroll
        for (int i = 0; i < ROWS; ++i) {
            h2reg[i] = val[i];
            if (act) bufA[i][tid] = val[i];
        }
    }
    __syncthreads();

    // ---- FF1 + relu ----
    gemm_phase4(bufA, W1, bufC, kg, jt);
    {
        float btid = act ? fb1[tid] : 0.f;
#pragma unroll
        for (int i = 0; i < ROWS; ++i) val[i] = act ? fmaxf(bufC[i][tid] + btid, 0.f) : 0.f;
    }
    __syncthreads();  // all FF1 reads of bufA done
    {
#pragma unroll
        for (int i = 0; i < ROWS; ++i)
            if (act) bufA[i][tid] = val[i];
    }
    __syncthreads();

    // ---- FF2 + residual(h2) + LN -> act_out (+ stage act for fused QKV) ----
    gemm_phase4(bufA, W2, bufC, kg, jt);
    {
        float btid = act ? fb2[tid] : 0.f;
#pragma unroll
        for (int i = 0; i < ROWS; ++i) val[i] = act ? (bufC[i][tid] + btid + h2reg[i]) : 0.f;
        ln4_1024(val, g2, lb2, red, act ? tid : 0, act);
    }
    __syncthreads();  // all FF2 reads of bufA done
    {
#pragma unroll
        for (int i = 0; i < ROWS; ++i) {
            if (act) {
                if (valid[i]) act_out[(size_t)(b * kS + r0 + i) * kE + tid] = val[i];
                bufA[i][tid] = val[i];
            }
        }
    }
    __syncthreads();

    // ---- fused QKV projection for next decoder block (row-local) ----
    if (Wqn != nullptr) {
#pragma unroll
        for (int slab = 0; slab < 3; ++slab) {
            gemm_phase4(bufA, Wqn + (size_t)slab * kE * kE, bufC, kg, jt);
            if (act) {
                float bj = bqn[slab * kE + tid];
#pragma unroll
                for (int i = 0; i < ROWS; ++i)
                    if (valid[i])
                        qkv_next[(size_t)(b * kS + r0 + i) * kQ + slab * kE + tid] =
                            bufC[i][tid] + bj;
            }
            __syncthreads();
        }
    }
}

// ---------------- logits: grid (157), 512 thr, 64 cols/block, 32 batch rows in LDS ----------
__global__ __launch_bounds__(512) void logits_k(const float* __restrict__ act3,
                                                const float* __restrict__ softW,
                                                const float* __restrict__ softb,
                                                float* __restrict__ logits, int tokm1) {
    __shared__ float xs[kB][kE];  // 64KB
    int tid = threadIdx.x;
    for (int p = tid; p < kB * kE; p += 512) {
        int bb = p >> 9, k = p & 511;
        xs[bb][k] = act3[(size_t)(bb * kS + tokm1) * kE + k];
    }
    __syncthreads();
    const int tx = tid & 31, ty = tid >> 5;  // ty 0..15 -> rows 2ty, 2ty+1
    int j0 = blockIdx.x * 64 + 2 * tx;
    int j0c = (j0 + 1 < kV) ? j0 : (kV - 2);
    float acc[2][2];
#pragma unroll
    for (int r = 0; r < 2; ++r) { acc[r][0] = softb[j0c]; acc[r][1] = softb[j0c + 1]; }
#pragma unroll 8
    for (int k = 0; k < kE; ++k) {
        const float2 wv = *(const float2*)(softW + (size_t)k * kV + j0c);
#pragma unroll
        for (int r = 0; r < 2; ++r) {
            float xv = xs[2 * ty + r][k];
            acc[r][0] = fmaf(xv, wv.x, acc[r][0]);
            acc[r][1] = fmaf(xv, wv.y, acc[r][1]);
        }
    }
    if (j0 + 1 < kV) {
#pragma unroll
        for (int r = 0; r < 2; ++r) {
            logits[(size_t)(2 * ty + r) * kV + j0] = acc[r][0];
            logits[(size_t)(2 * ty + r) * kV + j0 + 1] = acc[r][1];
        }
    } else if (j0 < kV) {
#pragma unroll
        for (int r = 0; r < 2; ++r) logits[(size_t)(2 * ty + r) * kV + j0] = acc[r][0];
    }
}

// ---------------- softmax + argmax + probs + Y row (512 threads) ----------------
__global__ __launch_bounds__(512) void softargmax_k(const float* __restrict__ logits,
                                                    float* __restrict__ outp,
                                                    const float* __restrict__ emb,
                                                    const float* __restrict__ pe_t,
                                                    float* __restrict__ Y, int tok) {
    __shared__ float redf[8];
    __shared__ int redi[8];
    int b = blockIdx.x, tid = threadIdx.x;
    const int lane = tid & 63, wid = tid >> 6;  // 8 waves
    const float* lg = logits + (size_t)b * kV;
    float m = -3.4e38f;
    int mi = 0;
    for (int j = tid; j < kV; j += 512) {
        float v = lg[j];
        if (v > m) { m = v; mi = j; }
    }
#pragma unroll
    for (int o = 32; o > 0; o >>= 1) {
        float m2 = __shfl_xor(m, o);
        int i2 = __shfl_xor(mi, o);
        if (m2 > m || (m2 == m && i2 < mi)) { m = m2; mi = i2; }
    }
    if (lane == 0) { redf[wid] = m; redi[wid] = mi; }
    __syncthreads();
    m = redf[0]; mi = redi[0];
#pragma unroll
    for (int wv = 1; wv < 8; ++wv) {
        if (redf[wv] > m || (redf[wv] == m && redi[wv] < mi)) { m = redf[wv]; mi = redi[wv]; }
    }
    __syncthreads();
    float ssum = 0.f;
    for (int j = tid; j < kV; j += 512) ssum += expf(lg[j] - m);
    {
#pragma unroll
        for (int o = 32; o > 0; o >>= 1) ssum += __shfl_xor(ssum, o);
        if (lane == 0) redf[wid] = ssum;
        __syncthreads();
        ssum = 0.f;
#pragma unroll
        for (int wv = 0; wv < 8; ++wv) ssum += redf[wv];
    }
    float inv = 1.f / ssum;
    float* orow = outp + (size_t)b * ((size_t)kS * kV);
    for (int j = tid; j < kV; j += 512) orow[j] = expf(lg[j] - m) * inv;
    const float* erow = emb + (size_t)mi * kE;
    float* yrow = Y + (size_t)(b * kS + tok) * kE;
    for (int j = tid; j < kE; j += 512) yrow[j] = erow[j] + pe_t[j];
}

// ---------------- qkv0 row for new token, batch-shared: grid (24) (R5-verified) ----------------
__global__ __launch_bounds__(256) void qkvrow_k(const float* __restrict__ Y,
                                                const float* __restrict__ Wq0,
                                                const float* __restrict__ bq0,
                                                float* __restrict__ qkv0, int tok) {
    __shared__ float ys[kB][kE];  // 64KB
    int tid = threadIdx.x;
    for (int p = tid; p < kB * kE; p += 256) {
        int bb = p >> 9, k = p & 511;
        ys[bb][k] = Y[(size_t)(bb * kS + tok) * kE + k];
    }
    __syncthreads();
    const int tx = tid & 63, ty = tid >> 6;
    const int j = blockIdx.x * 64 + tx;
    const float* Wc = Wq0 + (size_t)(j >> 9) * (kE * kE) + (j & 511);
    float acc[8];
    float bj = bq0[j];
#pragma unroll
    for (int i = 0; i < 8; ++i) acc[i] = bj;
#pragma unroll 4
    for (int k = 0; k < kE; k += 4) {
        float w0 = Wc[(size_t)(k + 0) * kE];
        float w1 = Wc[(size_t)(k + 1) * kE];
        float w2 = Wc[(size_t)(k + 2) * kE];
        float w3 = Wc[(size_t)(k + 3) * kE];
#pragma unroll
        for (int i = 0; i < 8; ++i) {
            const float4 yv = *(const float4*)(&ys[ty * 8 + i][k]);
            float a = acc[i];
            a = fmaf(yv.x, w0, a);
            a = fmaf(yv.y, w1, a);
            a = fmaf(yv.z, w2, a);
            a = fmaf(yv.w, w3, a);
            acc[i] = a;
        }
    }
#pragma unroll
    for (int i = 0; i < 8; ++i)
        qkv0[(size_t)((ty * 8 + i) * kS + tok) * kQ + j] = acc[i];
}

// ---------------- host ----------------
extern "C" void kernel_launch(void* const* d_in, const int* in_sizes, int n_in, void* d_out,
                              int out_size, void* d_ws, size_t ws_size, hipStream_t stream) {
    const float* noise = (const float*)d_in[0];
    const float* W_in = (const float*)d_in[1];
    const float* b_in = (const float*)d_in[2];
    const float* emb = (const float*)d_in[3];
    const float* Wsa = (const float*)d_in[4];
    const float* bsa = (const float*)d_in[5];
    const float* Wca = (const float*)d_in[6];
    const float* bca = (const float*)d_in[7];
    const float* Wff = (const float*)d_in[8];
    const float* bff = (const float*)d_in[9];
    const float* ln_g = (const float*)d_in[10];
    const float* ln_b = (const float*)d_in[11];
    const float* softW = (const float*)d_in[12];
    const float* softb = (const float*)d_in[13];
    float* out = (float*)d_out;
    (void)d_ws; (void)ws_size; (void)in_sizes; (void)n_in; (void)out_size;

    float *w_, *pe_, *Y_, *qkvb_, *actb_, *lg_, *U_, *a0_, *G_, *c0_, *ck_, *cv_;
    hipGetSymbolAddress((void**)&w_, HIP_SYMBOL(g_w));
    hipGetSymbolAddress((void**)&pe_, HIP_SYMBOL(g_pe));
    hipGetSymbolAddress((void**)&Y_, HIP_SYMBOL(g_Y));
    hipGetSymbolAddress((void**)&qkvb_, HIP_SYMBOL(g_qkvbuf));
    hipGetSymbolAddress((void**)&actb_, HIP_SYMBOL(g_actb));
    hipGetSymbolAddress((void**)&lg_, HIP_SYMBOL(g_logits));
    hipGetSymbolAddress((void**)&U_, HIP_SYMBOL(g_U));
    hipGetSymbolAddress((void**)&a0_, HIP_SYMBOL(g_a0));
    hipGetSymbolAddress((void**)&G_, HIP_SYMBOL(g_G));
    hipGetSymbolAddress((void**)&c0_, HIP_SYMBOL(g_c0));
    hipGetSymbolAddress((void**)&ck_, HIP_SYMBOL(g_ck));
    hipGetSymbolAddress((void**)&cv_, HIP_SYMBOL(g_cv));

    float* qb[kNB];
    float* ab[kNB];
    for (int n = 0; n < kNB; ++n) {
        qb[n] = qkvb_ + (size_t)n * (kB * kS * kQ);
        ab[n] = actb_ + (size_t)n * (kB * kS * kE);
    }

    dim3 blk(256);
    hipLaunchKernelGGL(onehot_k, dim3((kB * kV + 255) / 256), blk, 0, stream, out);
    hipLaunchKernelGGL(pe_k, dim3(kS * kE / 256), blk, 0, stream, pe_);
    hipLaunchKernelGGL(compute_w_k, dim3(1), dim3(1024), 0, stream, noise, W_in, b_in, w_);
    hipLaunchKernelGGL(initY_k, dim3(kB), blk, 0, stream, emb, pe_, Y_, Wsa, bsa, qb[0]);
    hipLaunchKernelGGL(colsum_k, dim3(kNB, 4), blk, 0, stream, Wca, ck_, cv_);
    hipLaunchKernelGGL(precross2_k, dim3(kNB, 4), blk, 0, stream, Wca, bca, ck_, cv_, U_, a0_,
                       G_, c0_);

    for (int tok = 1; tok < kS; ++tok) {
        const int t = tok;
        const int nch = (t + ROWS - 1) / ROWS;
        for (int n = 0; n < kNB; ++n) {
            const float* in_res = (n == 0) ? Y_ : ab[n - 1];
            const float* Wn = Wsa + (size_t)n * 4 * kE * kE;
            const float* bn = bsa + (size_t)n * 4 * kE;
            const float* Wf = Wff + (size_t)n * 2 * kE * kE;
            const float* bf = bff + (size_t)n * 2 * kE;
            const float* Wqn = (n < 3) ? (Wsa + (size_t)(n + 1) * 4 * kE * kE) : nullptr;
            const float* bqn = (n < 3) ? (bsa + (size_t)(n + 1) * 4 * kE) : bsa;
            float* qnext = (n < 3) ? qb[n + 1] : nullptr;
            // block 3's output is only consumed at row t-1 -> single chunk covering it
            const int grid_y = (n == 3) ? 1 : nch;
            const int r0_off = (n == 3) ? ((t > ROWS) ? (t - ROWS) : 0) : 0;
            hipLaunchKernelGGL(tail4w_k, dim3(kB, grid_y), dim3(TT), 0, stream,
                               qb[n], in_res,
                               Wn + 3 * kE * kE, bn + 3 * kE,
                               ln_g + (size_t)(n * 3 + 0) * kE, ln_b + (size_t)(n * 3 + 0) * kE,
                               U_ + n * kE * kH, a0_ + n * kH, G_ + n * kH * kE, c0_ + n * kE,
                               ln_g + (size_t)(n * 3 + 1) * kE, ln_b + (size_t)(n * 3 + 1) * kE,
                               Wf, bf, Wf + kE * kE, bf + kE,
                               ln_g + (size_t)(n * 3 + 2) * kE, ln_b + (size_t)(n * 3 + 2) * kE,
                               w_, ab[n], Wqn, bqn, qnext, t, r0_off);
        }
        hipLaunchKernelGGL(logits_k, dim3(157), dim3(512), 0, stream, ab[3], softW, softb, lg_,
                           tok - 1);
        hipLaunchKernelGGL(softargmax_k, dim3(kB), dim3(512), 0, stream, lg_,
                           out + (size_t)tok * kV, emb, pe_ + (size_t)tok * kE, Y_, tok);
        hipLaunchKernelGGL(qkvrow_k, dim3(24), blk, 0, stream, Y_, Wsa, bsa, qb[0], tok);
    }
}